// Round 1
// baseline (96.300 us; speedup 1.0000x reference)
//
#include <hip/hip_runtime.h>
#include <math.h>

#define NPIX 4096
#define NCH 256
#define NREF 32
#define THRESH 0.65f

// ws layout (float offsets):
// sim:          [0, 131072)         32 maps x 4096
// cellscore:    [131072, 139264)    32 x 256
// cellidx:      [139264, 147456)    (int) local idx in cell
// cellmin:      [147456, 155648)
// cellminflat:  [155648, 163840)    (int) global flat idx
// refden:       [163840, 163872)

__global__ __launch_bounds__(256) void k_refden(const float* __restrict__ ref,
                                                float* __restrict__ refden) {
    __shared__ float part[256];
    int t = threadIdx.x;
    int r = t >> 3, p = t & 7;
    float s = 0.f;
    for (int i = 0; i < 32; ++i) {
        float v = ref[r * NCH + p * 32 + i];
        s += v * v;
    }
    part[t] = s;
    __syncthreads();
    if (p == 0) {
        float tot = 0.f;
        for (int k = 0; k < 8; ++k) tot += part[r * 8 + k];
        refden[r] = sqrtf(tot) + 1e-12f;
    }
}

// 256 blocks x 256 threads; block handles 16 pixels, thread = (cg 0..15, pixoff 0..15)
__global__ __launch_bounds__(256) void k_sim(const float* __restrict__ feat,
                                             const float* __restrict__ ref,
                                             const float* __restrict__ refden,
                                             float* __restrict__ sim) {
    __shared__ __align__(16) float buf[NREF * NCH];  // normalized ref, then partial acc
    __shared__ float lnsq[256];
    __shared__ float lden[16];
    int t = threadIdx.x;
    for (int i = t; i < NREF * NCH; i += 256) buf[i] = ref[i] / refden[i >> 8];
    __syncthreads();

    int pixoff = t & 15, cg = t >> 4;
    int pbase = blockIdx.x * 16;
    const float* fp = feat + pbase + pixoff;
    float acc[NREF];
#pragma unroll
    for (int r = 0; r < NREF; ++r) acc[r] = 0.f;
    float nsq = 0.f;
    int c0 = cg * 16;
    for (int cc = 0; cc < 16; cc += 4) {
        int c = c0 + cc;
        float v0 = fp[(c + 0) * NPIX];
        float v1 = fp[(c + 1) * NPIX];
        float v2 = fp[(c + 2) * NPIX];
        float v3 = fp[(c + 3) * NPIX];
        nsq += v0 * v0; nsq += v1 * v1; nsq += v2 * v2; nsq += v3 * v3;
#pragma unroll
        for (int r = 0; r < NREF; ++r) {
            float4 w = *(const float4*)&buf[r * NCH + c];
            acc[r] += v0 * w.x + v1 * w.y + v2 * w.z + v3 * w.w;
        }
    }
    lnsq[t] = nsq;
    __syncthreads();  // all buf reads + lnsq writes done
#pragma unroll
    for (int r = 0; r < NREF; ++r) buf[r * 256 + t] = acc[r];
    if (t < 16) {
        float s = 0.f;
        for (int g = 0; g < 16; ++g) s += lnsq[g * 16 + t];
        lden[t] = sqrtf(s) + 1e-12f;
    }
    __syncthreads();
    for (int p = t; p < 512; p += 256) {
        int r = p >> 4, px = p & 15;
        float s = 0.f;
        for (int g = 0; g < 16; ++g) s += buf[r * 256 + g * 16 + px];
        sim[r * NPIX + pbase + px] = s / lden[px];
    }
}

// grid (256 cells, 32 maps) x 64 threads (1 wave). Thread t = local row in cell.
__global__ __launch_bounds__(64) void k_cells(const float* __restrict__ sim,
                                              float* __restrict__ cellscore,
                                              int* __restrict__ cellidx,
                                              float* __restrict__ cellmin,
                                              int* __restrict__ cellminflat) {
    __shared__ float P[36];  // 6x6 patch
    int cell = blockIdx.x;
    int map = blockIdx.y;
    int cy = cell >> 4, cx = cell & 15;
    int t = threadIdx.x;
    const float* sm = sim + map * NPIX;
    int ybase = 4 * cy - 1, xbase = 4 * cx - 1;
    if (t < 36) {
        int j = t / 6, i = t - 6 * j;
        int gy = min(max(ybase + j, 0), 63);
        int gx = min(max(xbase + i, 0), 63);
        P[t] = sm[gy * 64 + gx];
    }
    __syncthreads();

    int oy = cy * 64 + t;
    float fy = (oy + 0.5f) * 0.0625f - 0.5f;  // exact dyadic
    float y0f = floorf(fy);
    int y0 = (int)y0f;
    float wy = fy - y0f;  // exact
    bool ylo = fy < 0.0f, yhi = fy > 63.0f;
    int py0 = min(max(y0, 0), 63) - ybase;      // 0..5
    int py1 = min(max(y0 + 1, 0), 63) - ybase;  // 0..5
    const float* P0 = &P[py0 * 6];
    const float* P1 = &P[py1 * 6];

    float bmax = -1e30f; int bmaxi = 0;
    float bmin = 1e30f;  int bmini = 0;
    const int lstart[5] = {0, 8, 24, 40, 56};
    const int lend[5]   = {8, 24, 40, 56, 64};
    float w1y = 1.0f - wy;
#pragma unroll
    for (int s = 0; s < 5; ++s) {
        float a = P0[s], b = P0[s + 1];
        float c = P1[s], d = P1[s + 1];
        // y-combine first (mirrors reference dim order), with exact edge passthrough
        float q0 = ylo ? a : (yhi ? c : w1y * a + wy * c);
        float q1 = ylo ? b : (yhi ? d : w1y * b + wy * d);
        int x0 = xbase + s;
        float x0f = (float)x0;
        for (int l = lstart[s]; l < lend[s]; ++l) {
            int ox = cx * 64 + l;
            float fx = (ox + 0.5f) * 0.0625f - 0.5f;
            float wx = fx - x0f;
            float v;
            if (fx < 0.0f)        v = q1;  // single tap at col 0
            else if (fx > 63.0f)  v = q0;  // single tap at col 63
            else                  v = (1.0f - wx) * q0 + wx * q1;
            int li = t * 64 + l;
            if (v > bmax) { bmax = v; bmaxi = li; }
            if (v < bmin) { bmin = v; bmini = oy * 1024 + ox; }
        }
    }
    // wave-64 reduce, tie-break to smaller index (first occurrence semantics)
    for (int off = 32; off > 0; off >>= 1) {
        float ov = __shfl_down(bmax, off);
        int   oi = __shfl_down(bmaxi, off);
        if (ov > bmax || (ov == bmax && oi < bmaxi)) { bmax = ov; bmaxi = oi; }
        float mv = __shfl_down(bmin, off);
        int   mi = __shfl_down(bmini, off);
        if (mv < bmin || (mv == bmin && mi < bmini)) { bmin = mv; bmini = mi; }
    }
    if (t == 0) {
        cellscore[map * 256 + cell] = bmax;
        cellidx[map * 256 + cell] = bmaxi;
        cellmin[map * 256 + cell] = bmin;
        cellminflat[map * 256 + cell] = bmini;
    }
}

// 32 blocks (one per map) x 256 threads (one per cell)
__global__ __launch_bounds__(256) void k_out(const float* __restrict__ cellscore,
                                             const int* __restrict__ cellidx,
                                             const float* __restrict__ cellmin,
                                             const int* __restrict__ cellminflat,
                                             float* __restrict__ out) {
    __shared__ float sc[256];
    __shared__ float mvs[256];
    __shared__ int mis[256];
    int m = blockIdx.x, t = threadIdx.x;
    float score = cellscore[m * 256 + t];
    int li = cellidx[m * 256 + t];
    int cy = t >> 4, cx = t & 15;
    int ly = li >> 6, lx = li & 63;
    bool valid = score > THRESH;
    float px = valid ? (float)(cx * 64 + lx) : -1.0f;
    float py = valid ? (float)(cy * 64 + ly) : -1.0f;
    float ps = valid ? score : -1.0f;
    sc[t] = ps;
    mvs[t] = cellmin[m * 256 + t];
    mis[t] = cellminflat[m * 256 + t];
    __syncthreads();
    // stable descending rank: key (-score, cell_id)
    int rank = 0;
    for (int j = 0; j < 256; ++j) {
        float sj = sc[j];
        rank += (sj > ps || (sj == ps && j < t)) ? 1 : 0;
    }
    float* o = out + m * 768 + rank * 3;
    o[0] = px; o[1] = py; o[2] = ps;
    // bg: lexicographic min (val, flat idx)
    for (int s = 128; s > 0; s >>= 1) {
        __syncthreads();
        if (t < s) {
            float v2 = mvs[t + s]; int i2 = mis[t + s];
            if (v2 < mvs[t] || (v2 == mvs[t] && i2 < mis[t])) { mvs[t] = v2; mis[t] = i2; }
        }
    }
    __syncthreads();
    if (t == 0) {
        int idx = mis[0];
        out[24576 + m * 2 + 0] = (float)(idx % 1024);  // x = col
        out[24576 + m * 2 + 1] = (float)(idx / 1024);  // y = row
    }
}

extern "C" void kernel_launch(void* const* d_in, const int* in_sizes, int n_in,
                              void* d_out, int out_size, void* d_ws, size_t ws_size,
                              hipStream_t stream) {
    const float* feat = (const float*)d_in[0];  // (1,256,64,64)
    const float* ref  = (const float*)d_in[1];  // (32,1,256)
    if (in_sizes[0] == NREF * NCH) {  // defensive: swap if order reversed
        feat = (const float*)d_in[1];
        ref  = (const float*)d_in[0];
    }
    float* out = (float*)d_out;
    float* ws = (float*)d_ws;
    float* sim         = ws;
    float* cellscore   = ws + 131072;
    int*   cellidx     = (int*)(ws + 139264);
    float* cellmin     = ws + 147456;
    int*   cellminflat = (int*)(ws + 155648);
    float* refden      = ws + 163840;

    k_refden<<<1, 256, 0, stream>>>(ref, refden);
    k_sim<<<256, 256, 0, stream>>>(feat, ref, refden, sim);
    k_cells<<<dim3(256, 32), 64, 0, stream>>>(sim, cellscore, cellidx, cellmin, cellminflat);
    k_out<<<32, 256, 0, stream>>>(cellscore, cellidx, cellmin, cellminflat, out);
}